// Round 9
// baseline (863.148 us; speedup 1.0000x reference)
//
#include <hip/hip_runtime.h>
#include <math.h>

// ---------------- LDS layout for token kernel (floats) ----------------
#define O_WQ   0
#define O_WK   576
#define O_WV   1152
#define O_RELK 1728
#define O_RELV 1836
#define O_W1   1944
#define O_W2   4248
#define O_BQ   6552
#define O_BK   6576
#define O_BV   6600
#define O_B1   6624
#define O_B2   6720
#define O_GA   6744
#define O_BA   6768
#define O_GF   6792
#define O_BF   6816
#define O_PE   6840                 // 504, transposed [f][s]
#define O_IN   7344                 // [12 tokens][504] input, PRESERVED (x read on the fly)
#define O_KV   13392                // [12 tokens][504] k -> v -> ff out
#define SM_TOT 19440                // 77760 B -> 2 blocks/CU

// ---------------- repetition macros ----------------
#define REP8(M)  M(0) M(1) M(2) M(3) M(4) M(5) M(6) M(7)
#define REP12(M) REP8(M) M(8) M(9) M(10) M(11)
#define REP21(M) REP12(M) M(12) M(13) M(14) M(15) M(16) M(17) M(18) M(19) M(20)
#define REP24(M) REP21(M) M(21) M(22) M(23)

// vector loads (no pointer temp -> no name collisions)
#define LD3(bp,A,B,C) \
  float4 A=*(const float4*)((bp)+0), B=*(const float4*)((bp)+4), C=*(const float4*)((bp)+8);
#define LD6(bp,A,B,C,D,E,F) LD3(bp,A,B,C) \
  float4 D=*(const float4*)((bp)+12), E=*(const float4*)((bp)+16), F=*(const float4*)((bp)+20);

// P##0..11 += xs * {A,B,C}
#define FMA12L(P,xs,A,B,C) \
  P##0 =fmaf(xs,A.x,P##0 ); P##1 =fmaf(xs,A.y,P##1 ); P##2 =fmaf(xs,A.z,P##2 ); P##3 =fmaf(xs,A.w,P##3 ); \
  P##4 =fmaf(xs,B.x,P##4 ); P##5 =fmaf(xs,B.y,P##5 ); P##6 =fmaf(xs,B.z,P##6 ); P##7 =fmaf(xs,B.w,P##7 ); \
  P##8 =fmaf(xs,C.x,P##8 ); P##9 =fmaf(xs,C.y,P##9 ); P##10=fmaf(xs,C.z,P##10); P##11=fmaf(xs,C.w,P##11);
// P##12..23 += xs * {A,B,C}
#define FMA12H(P,xs,A,B,C) \
  P##12=fmaf(xs,A.x,P##12); P##13=fmaf(xs,A.y,P##13); P##14=fmaf(xs,A.z,P##14); P##15=fmaf(xs,A.w,P##15); \
  P##16=fmaf(xs,B.x,P##16); P##17=fmaf(xs,B.y,P##17); P##18=fmaf(xs,B.z,P##18); P##19=fmaf(xs,B.w,P##19); \
  P##20=fmaf(xs,C.x,P##20); P##21=fmaf(xs,C.y,P##21); P##22=fmaf(xs,C.z,P##22); P##23=fmaf(xs,C.w,P##23);
#define FMA24(P,xs,A,B,C,D,E,F) FMA12L(P,xs,A,B,C) FMA12H(P,xs,D,E,F)

// x value read on the fly from preserved input tile (+posenc)
#define XR(j) (tin[(j)*21 + s] + sm[O_PE + (j)*21 + s])

// one W-row update: P##0..23 += x(j) * W[j][0..23]
#define WJ(j,W,P) { const float xj_ = XR(j); LD6(&sm[(W)+(j)*24], wA,wB,wC,wD,wE,wF) \
                    FMA24(P,xj_,wA,wB,wC,wD,wE,wF) }
#define REPW24(W,P) WJ(0,W,P) WJ(1,W,P) WJ(2,W,P) WJ(3,W,P) WJ(4,W,P) WJ(5,W,P) \
  WJ(6,W,P) WJ(7,W,P) WJ(8,W,P) WJ(9,W,P) WJ(10,W,P) WJ(11,W,P) WJ(12,W,P) WJ(13,W,P) \
  WJ(14,W,P) WJ(15,W,P) WJ(16,W,P) WJ(17,W,P) WJ(18,W,P) WJ(19,W,P) WJ(20,W,P) \
  WJ(21,W,P) WJ(22,W,P) WJ(23,W,P)

// ---------------- kernel 0: positional encoding table (transposed [f][s]) ----------------
__global__ void posenc_kernel(float* __restrict__ pe) {
    int i = threadIdx.x;
    if (i < 504) {
        int f = i / 21, s = i % 21;
        double e = (double)(2 * (f / 2)) / 24.0;
        double ang = (double)s / pow(10000.0, e);
        float v = (f & 1) ? cosf((float)ang) : sinf((float)ang);
        pe[i] = 0.01f * v + 0.01f;   // folded *0.01 + 0.01
    }
}

// ---------------- kernel 1: fused per-token transformer, one row per lane ----------------
// Live-register budget engineered to stay under ~80 floats at every point
// (allocator empirically parks at 84 VGPRs and spills the excess: rounds 2-8).
// x stays in LDS (input preserved); heads processed separately; ff hidden in 12-chunks.
__global__ __launch_bounds__(256, 2) void token_kernel(
    const float* __restrict__ inp,
    const float* __restrict__ wq, const float* __restrict__ bq,
    const float* __restrict__ wk, const float* __restrict__ bk,
    const float* __restrict__ wv, const float* __restrict__ bv,
    const float* __restrict__ relk, const float* __restrict__ relv,
    const float* __restrict__ ga, const float* __restrict__ ba,
    const float* __restrict__ w1, const float* __restrict__ b1,
    const float* __restrict__ w2, const float* __restrict__ b2,
    const float* __restrict__ gf, const float* __restrict__ bf,
    const float* __restrict__ pe, float* __restrict__ ffout, int ntok)
{
    __shared__ __align__(16) float sm[SM_TOT];
    const int tid  = threadIdx.x;
    const int lane = tid & 63;
    const int wv_  = tid >> 6;

    // ---- coalesced input staging: wave's 3 tokens -> PRESERVED input tile ----
    {
        const size_t lim4  = (size_t)ntok * 126;
        const size_t base4 = ((size_t)blockIdx.x * 12 + wv_ * 3) * 126;
        const float4* in4 = (const float4*)inp;
        float4* t4 = (float4*)&sm[O_IN + wv_ * 1512];
        #pragma unroll
        for (int c = 0; c < 6; ++c) {
            int idx = lane + c * 64;
            if (idx < 378) {
                float4 v4 = make_float4(0.f, 0.f, 0.f, 0.f);
                if (base4 + idx < lim4) v4 = in4[base4 + idx];
                t4[idx] = v4;
            }
        }
    }

    // ---- cooperative weight staging ----
    for (int i = tid; i < 576; i += 256) { sm[O_WQ+i]=wq[i]; sm[O_WK+i]=wk[i]; sm[O_WV+i]=wv[i]; }
    for (int i = tid; i < 2304; i += 256) { sm[O_W1+i]=w1[i]; sm[O_W2+i]=w2[i]; }
    if (tid < 108) { sm[O_RELK+tid]=relk[tid]; sm[O_RELV+tid]=relv[tid]; }
    if (tid < 24) { sm[O_BQ+tid]=bq[tid]; sm[O_BK+tid]=bk[tid]; sm[O_BV+tid]=bv[tid];
                    sm[O_B2+tid]=b2[tid]; sm[O_GA+tid]=ga[tid]; sm[O_BA+tid]=ba[tid];
                    sm[O_GF+tid]=gf[tid]; sm[O_BF+tid]=bf[tid]; }
    if (tid >= 128 && tid < 224) sm[O_B1+tid-128] = b1[tid-128];
    for (int i = tid; i < 504; i += 256) sm[O_PE+i] = pe[i];
    __syncthreads();

    // ---- lane -> (token t, row s) ----
    int t = lane / 21;
    int s = lane - t * 21;
    if (lane == 63) { t = 2; s = 20; }     // dummy lane mirrors lane 62 (benign dup writes)
    const float* tin = &sm[O_IN + (wv_*3 + t) * 504];
    float* kvt   = &sm[O_KV + (wv_*3 + t) * 504];
    float* myrow = kvt + s * 24;

    // ---- k = relu(x@Wk+bk) -> KV tile ----
    {
#define DKK(i) float kk##i = sm[O_BK+(i)];
        REP24(DKK)
        REPW24(O_WK, kk)
        *(float4*)(myrow+ 0) = make_float4(fmaxf(kk0 ,0.f),fmaxf(kk1 ,0.f),fmaxf(kk2 ,0.f),fmaxf(kk3 ,0.f));
        *(float4*)(myrow+ 4) = make_float4(fmaxf(kk4 ,0.f),fmaxf(kk5 ,0.f),fmaxf(kk6 ,0.f),fmaxf(kk7 ,0.f));
        *(float4*)(myrow+ 8) = make_float4(fmaxf(kk8 ,0.f),fmaxf(kk9 ,0.f),fmaxf(kk10,0.f),fmaxf(kk11,0.f));
        *(float4*)(myrow+12) = make_float4(fmaxf(kk12,0.f),fmaxf(kk13,0.f),fmaxf(kk14,0.f),fmaxf(kk15,0.f));
        *(float4*)(myrow+16) = make_float4(fmaxf(kk16,0.f),fmaxf(kk17,0.f),fmaxf(kk18,0.f),fmaxf(kk19,0.f));
        *(float4*)(myrow+20) = make_float4(fmaxf(kk20,0.f),fmaxf(kk21,0.f),fmaxf(kk22,0.f),fmaxf(kk23,0.f));
    }

    // ---- q = relu(x@Wq+bq) (k-write latency hides under this) ----
#define DQQ(i) float q##i = sm[O_BQ+(i)];
    REP24(DQQ)
    REPW24(O_WQ, q)
#define RQ(i) q##i = fmaxf(q##i, 0.f);
    REP24(RQ)
    asm volatile("s_waitcnt lgkmcnt(0)" ::: "memory");   // wave's k writes visible

    // ---- logits, head 0 then head 1 (12-wide halves -> small temp set) ----
    const float rsc = 0.28867513459481287f;   // 1/sqrt(12)
#define DP_(i) float p0_##i, p1_##i;
    REP21(DP_)
#define LGT0(ks) { \
    int dd=(ks)-s; dd=dd<-4?-4:(dd>4?4:dd); dd+=4; \
    LD3(kvt + (ks)*24, kA,kB,kC) \
    LD3(&sm[O_RELK + dd*12], rA,rB,rC) \
    float a_=0.f; \
    a_=fmaf(q0 ,kA.x+rA.x,a_); a_=fmaf(q1 ,kA.y+rA.y,a_); a_=fmaf(q2 ,kA.z+rA.z,a_); a_=fmaf(q3 ,kA.w+rA.w,a_); \
    a_=fmaf(q4 ,kB.x+rB.x,a_); a_=fmaf(q5 ,kB.y+rB.y,a_); a_=fmaf(q6 ,kB.z+rB.z,a_); a_=fmaf(q7 ,kB.w+rB.w,a_); \
    a_=fmaf(q8 ,kC.x+rC.x,a_); a_=fmaf(q9 ,kC.y+rC.y,a_); a_=fmaf(q10,kC.z+rC.z,a_); a_=fmaf(q11,kC.w+rC.w,a_); \
    p0_##ks = a_*rsc; }
    REP21(LGT0)
#define LGT1(ks) { \
    int dd=(ks)-s; dd=dd<-4?-4:(dd>4?4:dd); dd+=4; \
    LD3(kvt + (ks)*24 + 12, kA,kB,kC) \
    LD3(&sm[O_RELK + dd*12], rA,rB,rC) \
    float a_=0.f; \
    a_=fmaf(q12,kA.x+rA.x,a_); a_=fmaf(q13,kA.y+rA.y,a_); a_=fmaf(q14,kA.z+rA.z,a_); a_=fmaf(q15,kA.w+rA.w,a_); \
    a_=fmaf(q16,kB.x+rB.x,a_); a_=fmaf(q17,kB.y+rB.y,a_); a_=fmaf(q18,kB.z+rB.z,a_); a_=fmaf(q19,kB.w+rB.w,a_); \
    a_=fmaf(q20,kC.x+rC.x,a_); a_=fmaf(q21,kC.y+rC.y,a_); a_=fmaf(q22,kC.z+rC.z,a_); a_=fmaf(q23,kC.w+rC.w,a_); \
    p1_##ks = a_*rsc; }
    REP21(LGT1)

    // ---- softmax (q dead now) ----
    {
        float m0 = p0_0, m1 = p1_0;
#define MX(i) m0 = fmaxf(m0, p0_##i); m1 = fmaxf(m1, p1_##i);
        REP21(MX)
        float sum0 = 0.f, sum1 = 0.f;
#define EX(i) p0_##i = __expf(p0_##i - m0); sum0 += p0_##i; \
              p1_##i = __expf(p1_##i - m1); sum1 += p1_##i;
        REP21(EX)
        float is0 = 1.f/sum0, is1 = 1.f/sum1;
#define NM(i) p0_##i *= is0; p1_##i *= is1;
        REP21(NM)
    }

    // ---- v = relu(x@Wv+bv) -> KV tile (k reads retired; input tile untouched) ----
    asm volatile("s_waitcnt lgkmcnt(0)" ::: "memory");
    {
#define DVV(i) float vv##i = sm[O_BV+(i)];
        REP24(DVV)
        REPW24(O_WV, vv)
        *(float4*)(myrow+ 0) = make_float4(fmaxf(vv0 ,0.f),fmaxf(vv1 ,0.f),fmaxf(vv2 ,0.f),fmaxf(vv3 ,0.f));
        *(float4*)(myrow+ 4) = make_float4(fmaxf(vv4 ,0.f),fmaxf(vv5 ,0.f),fmaxf(vv6 ,0.f),fmaxf(vv7 ,0.f));
        *(float4*)(myrow+ 8) = make_float4(fmaxf(vv8 ,0.f),fmaxf(vv9 ,0.f),fmaxf(vv10,0.f),fmaxf(vv11,0.f));
        *(float4*)(myrow+12) = make_float4(fmaxf(vv12,0.f),fmaxf(vv13,0.f),fmaxf(vv14,0.f),fmaxf(vv15,0.f));
        *(float4*)(myrow+16) = make_float4(fmaxf(vv16,0.f),fmaxf(vv17,0.f),fmaxf(vv18,0.f),fmaxf(vv19,0.f));
        *(float4*)(myrow+20) = make_float4(fmaxf(vv20,0.f),fmaxf(vv21,0.f),fmaxf(vv22,0.f),fmaxf(vv23,0.f));
    }
    asm volatile("s_waitcnt lgkmcnt(0)" ::: "memory");

    // ---- o = p · (v + rel_v), head 0 then head 1 ----
#define DO_(i) float o##i = 0.f;
    REP24(DO_)
#define OT0(ks) { \
    int dd=(ks)-s; dd=dd<-4?-4:(dd>4?4:dd); dd+=4; \
    LD3(kvt + (ks)*24, vA,vB,vC) \
    LD3(&sm[O_RELV + dd*12], rA,rB,rC) \
    const float w_ = p0_##ks; \
    o0 =fmaf(w_,vA.x+rA.x,o0 ); o1 =fmaf(w_,vA.y+rA.y,o1 ); o2 =fmaf(w_,vA.z+rA.z,o2 ); o3 =fmaf(w_,vA.w+rA.w,o3 ); \
    o4 =fmaf(w_,vB.x+rB.x,o4 ); o5 =fmaf(w_,vB.y+rB.y,o5 ); o6 =fmaf(w_,vB.z+rB.z,o6 ); o7 =fmaf(w_,vB.w+rB.w,o7 ); \
    o8 =fmaf(w_,vC.x+rC.x,o8 ); o9 =fmaf(w_,vC.y+rC.y,o9 ); o10=fmaf(w_,vC.z+rC.z,o10); o11=fmaf(w_,vC.w+rC.w,o11); }
    REP21(OT0)
#define OT1(ks) { \
    int dd=(ks)-s; dd=dd<-4?-4:(dd>4?4:dd); dd+=4; \
    LD3(kvt + (ks)*24 + 12, vA,vB,vC) \
    LD3(&sm[O_RELV + dd*12], rA,rB,rC) \
    const float w_ = p1_##ks; \
    o12=fmaf(w_,vA.x+rA.x,o12); o13=fmaf(w_,vA.y+rA.y,o13); o14=fmaf(w_,vA.z+rA.z,o14); o15=fmaf(w_,vA.w+rA.w,o15); \
    o16=fmaf(w_,vB.x+rB.x,o16); o17=fmaf(w_,vB.y+rB.y,o17); o18=fmaf(w_,vB.z+rB.z,o18); o19=fmaf(w_,vB.w+rB.w,o19); \
    o20=fmaf(w_,vC.x+rC.x,o20); o21=fmaf(w_,vC.y+rC.y,o21); o22=fmaf(w_,vC.z+rC.z,o22); o23=fmaf(w_,vC.w+rC.w,o23); }
    REP21(OT1)

    // ---- attn = LN(o + x)  (x re-read from preserved input tile) ----
#define ATD(i) float at##i = o##i + XR(i);
    REP24(ATD)
    {
        float sA = 0.f, sB = 0.f;
#define ASUM(i) sA += at##i; sB = fmaf(at##i, at##i, sB);
        REP24(ASUM)
        float mn = sA * (1.f/24.f);
        float rstd = rsqrtf(sB*(1.f/24.f) - mn*mn + 1e-3f);
#define ALN(i) at##i = fmaf(sm[O_GA+(i)], (at##i - mn)*rstd, sm[O_BA+(i)]);
        REP24(ALN)
    }

    // ---- ff = relu(at@w1+b1)@w2 + b2, hidden in 12-wide chunks ----
#define DFF(i) float ff##i = sm[O_B2+(i)];
    REP24(DFF)
    for (int cc = 0; cc < 96; cc += 12) {
#define DH(i) float h##i = sm[O_B1 + cc + (i)];
        REP12(DH)
#define HJ(j) { const float aj_ = at##j; LD3(&sm[O_W1+(j)*96+cc], wA,wB,wC) \
                FMA12L(h,aj_,wA,wB,wC) }
        REP24(HJ)
#define RH(i) h##i = fmaxf(h##i, 0.f);
        REP12(RH)
#define FL(l) { const float hl_ = h##l; \
                { LD3(&sm[O_W2+(cc+(l))*24], wA,wB,wC) FMA12L(ff,hl_,wA,wB,wC) } \
                { LD3(&sm[O_W2+(cc+(l))*24+12], wD,wE,wF) FMA12H(ff,hl_,wD,wE,wF) } }
        REP12(FL)
    }

    // ---- ff = LN(ff + at) ----
    {
#define FR(i) ff##i += at##i;
        REP24(FR)
        float sC = 0.f, sD = 0.f;
#define FSUM(i) sC += ff##i; sD = fmaf(ff##i, ff##i, sD);
        REP24(FSUM)
        float mn2 = sC * (1.f/24.f);
        float rstd2 = rsqrtf(sD*(1.f/24.f) - mn2*mn2 + 1e-3f);
#define FLN(i) ff##i = fmaf(sm[O_GF+(i)], (ff##i - mn2)*rstd2, sm[O_BF+(i)]);
        REP24(FLN)
    }

    // ---- transpose via KV tile (v reads retired), then coalesced store ----
#define STF(i) kvt[(i)*21 + s] = ff##i;
    REP24(STF)
    asm volatile("s_waitcnt lgkmcnt(0)" ::: "memory");
    {
        const size_t lim4  = (size_t)ntok * 126;
        const size_t base4 = ((size_t)blockIdx.x * 12 + wv_ * 3) * 126;
        float4* out4 = (float4*)ffout;
        const float4* t4 = (const float4*)&sm[O_KV + wv_ * 1512];
        #pragma unroll
        for (int c = 0; c < 6; ++c) {
            int idx = lane + c * 64;
            if (idx < 378 && base4 + idx < lim4)
                out4[base4 + idx] = t4[idx];
        }
    }
}

// ---------------- kernel 2: [N,504]@[504,512] + bias + relu (LN separate) ----------------
// 64 rows x 256 cols per block (gridDim.y=2 col blocks). acc 8x8 = 64 regs:
// spill-proof even under the allocator's 84-VGPR preference.
#define DN_LDA 68
__global__ __launch_bounds__(256, 4) void dense_kernel(
    const float* __restrict__ A, const float* __restrict__ wd,
    const float* __restrict__ bd, float* __restrict__ out)
{
    __shared__ __align__(16) float At[24*DN_LDA];   // 1632 floats
    __shared__ __align__(16) float Bs[24*256];      // 6144 floats
    const int tid  = threadIdx.x;
    const int w    = tid >> 6;
    const int lane = tid & 63;
    const int lr   = lane >> 3;
    const int lc   = lane & 7;
    const int row0 = blockIdx.x * 64;
    const int col0 = blockIdx.y * 256;
    const int wcol = w*64 + lc*8;        // col within block

    float acc[8][8];
    #pragma unroll
    for (int r = 0; r < 8; ++r)
        #pragma unroll
        for (int j = 0; j < 8; ++j) acc[r][j] = 0.f;

    for (int k0 = 0; k0 < 504; k0 += 24) {
        __syncthreads();
        #pragma unroll
        for (int i = 0; i < 6; ++i) {
            int ii = tid + i*256;                 // 1536 = 64 rows x 24 kk
            int r = ii / 24, kk = ii - r*24;
            At[kk*DN_LDA + r] = A[(size_t)(row0 + r)*504 + k0 + kk];
        }
        const float4* wd4 = (const float4*)wd;    // row stride 128 float4
        float4* Bs4 = (float4*)Bs;
        #pragma unroll
        for (int c = 0; c < 6; ++c) {
            int idx = tid + c*256;                // 1536 float4 = 24 kk x 64
            int kk = idx >> 6, c4 = idx & 63;
            Bs4[kk*64 + c4] = wd4[(size_t)(k0 + kk)*128 + (col0 >> 2) + c4];
        }
        __syncthreads();

        #pragma unroll
        for (int kk = 0; kk < 24; ++kk) {
            float4 a0 = *(const float4*)&At[kk*DN_LDA + lr*8];
            float4 a1 = *(const float4*)&At[kk*DN_LDA + lr*8 + 4];
            float4 b0 = *(const float4*)&Bs[kk*256 + wcol];
            float4 b1 = *(const float4*)&Bs[kk*256 + wcol + 4];
            float av[8] = {a0.x,a0.y,a0.z,a0.w,a1.x,a1.y,a1.z,a1.w};
            float bv[8] = {b0.x,b0.y,b0.z,b0.w,b1.x,b1.y,b1.z,b1.w};
            #pragma unroll
            for (int r = 0; r < 8; ++r)
                #pragma unroll
                for (int j = 0; j < 8; ++j)
                    acc[r][j] = fmaf(av[r], bv[j], acc[r][j]);
        }
    }

    float4 bias0 = *(const float4*)&bd[col0 + wcol];
    float4 bias1 = *(const float4*)&bd[col0 + wcol + 4];
    #pragma unroll
    for (int r = 0; r < 8; ++r) {
        float* orow = out + (size_t)(row0 + lr*8 + r)*512 + col0;
        float4 o4;
        o4.x = fmaxf(acc[r][0] + bias0.x, 0.f);
        o4.y = fmaxf(acc[r][1] + bias0.y, 0.f);
        o4.z = fmaxf(acc[r][2] + bias0.z, 0.f);
        o4.w = fmaxf(acc[r][3] + bias0.w, 0.f);
        *(float4*)&orow[wcol] = o4;
        o4.x = fmaxf(acc[r][4] + bias1.x, 0.f);
        o4.y = fmaxf(acc[r][5] + bias1.y, 0.f);
        o4.z = fmaxf(acc[r][6] + bias1.z, 0.f);
        o4.w = fmaxf(acc[r][7] + bias1.w, 0.f);
        *(float4*)&orow[wcol + 4] = o4;
    }
}

// ---------------- kernel 3: in-place LN over 512 cols, one row per wave ----------------
__global__ __launch_bounds__(256, 4) void ln512_kernel(
    float* __restrict__ out, const float* __restrict__ g, const float* __restrict__ b)
{
    const int lane = threadIdx.x & 63;
    const size_t row = (size_t)blockIdx.x * 4 + (threadIdx.x >> 6);
    float4* p = (float4*)(out + row*512) + lane*2;
    float4 v0 = p[0], v1 = p[1];
    float s1 = v0.x+v0.y+v0.z+v0.w + v1.x+v1.y+v1.z+v1.w;
    float s2 = 0.f;
    s2 = fmaf(v0.x,v0.x,s2); s2 = fmaf(v0.y,v0.y,s2); s2 = fmaf(v0.z,v0.z,s2); s2 = fmaf(v0.w,v0.w,s2);
    s2 = fmaf(v1.x,v1.x,s2); s2 = fmaf(v1.y,v1.y,s2); s2 = fmaf(v1.z,v1.z,s2); s2 = fmaf(v1.w,v1.w,s2);
    #pragma unroll
    for (int off = 32; off > 0; off >>= 1) {
        s1 += __shfl_xor(s1, off);
        s2 += __shfl_xor(s2, off);
    }
    float m  = s1 * (1.f/512.f);
    float rs = rsqrtf(s2 * (1.f/512.f) - m*m + 1e-3f);
    const float4* g4 = (const float4*)g + lane*2;
    const float4* b4 = (const float4*)b + lane*2;
    float4 ga0 = g4[0], ga1 = g4[1], bb0 = b4[0], bb1 = b4[1];
    v0.x = fmaf(ga0.x, (v0.x-m)*rs, bb0.x);
    v0.y = fmaf(ga0.y, (v0.y-m)*rs, bb0.y);
    v0.z = fmaf(ga0.z, (v0.z-m)*rs, bb0.z);
    v0.w = fmaf(ga0.w, (v0.w-m)*rs, bb0.w);
    v1.x = fmaf(ga1.x, (v1.x-m)*rs, bb1.x);
    v1.y = fmaf(ga1.y, (v1.y-m)*rs, bb1.y);
    v1.z = fmaf(ga1.z, (v1.z-m)*rs, bb1.z);
    v1.w = fmaf(ga1.w, (v1.w-m)*rs, bb1.w);
    p[0] = v0; p[1] = v1;
}

extern "C" void kernel_launch(void* const* d_in, const int* in_sizes, int n_in,
                              void* d_out, int out_size, void* d_ws, size_t ws_size,
                              hipStream_t stream)
{
    const float* inp  = (const float*)d_in[0];
    const float* wq   = (const float*)d_in[1];
    const float* bq   = (const float*)d_in[2];
    const float* wk   = (const float*)d_in[3];
    const float* bk   = (const float*)d_in[4];
    const float* wv   = (const float*)d_in[5];
    const float* bv   = (const float*)d_in[6];
    const float* relk = (const float*)d_in[7];
    const float* relv = (const float*)d_in[8];
    const float* ga   = (const float*)d_in[9];
    const float* ba   = (const float*)d_in[10];
    const float* w1   = (const float*)d_in[11];
    const float* b1   = (const float*)d_in[12];
    const float* w2   = (const float*)d_in[13];
    const float* b2   = (const float*)d_in[14];
    const float* gf   = (const float*)d_in[15];
    const float* bf   = (const float*)d_in[16];
    const float* wd   = (const float*)d_in[17];
    const float* bd   = (const float*)d_in[18];
    const float* go_  = (const float*)d_in[19];
    const float* bo_  = (const float*)d_in[20];

    float* ws = (float*)d_ws;
    float* pe = ws;             // 504 floats (transposed [f][s])
    float* ff = ws + 512;       // N*504 floats
    const int N = in_sizes[0] / 504;   // 32768

    hipLaunchKernelGGL(posenc_kernel, dim3(1), dim3(512), 0, stream, pe);
    hipLaunchKernelGGL(token_kernel, dim3((N + 11) / 12), dim3(256), 0, stream,
                       inp, wq, bq, wk, bk, wv, bv, relk, relv, ga, ba,
                       w1, b1, w2, b2, gf, bf, pe, ff, N);
    hipLaunchKernelGGL(dense_kernel, dim3(N/64, 2), dim3(256), 0, stream,
                       ff, wd, bd, (float*)d_out);
    hipLaunchKernelGGL(ln512_kernel, dim3(N/4), dim3(256), 0, stream,
                       (float*)d_out, go_, bo_);
}